// Round 1
// baseline (9508.967 us; speedup 1.0000x reference)
//
#include <hip/hip_runtime.h>
#include <math.h>

namespace {
constexpr int B = 8, T = 64, N = 2048, H = 64, F = 64, E = 32768, G = 192;
constexpr int BNH = B * N * H;   // 1048576
}

__device__ __forceinline__ float bcastf(float v, int l) {
  return __uint_as_float(__builtin_amdgcn_readlane(__float_as_uint(v), l));
}

// ---------------- setup kernels ----------------

__global__ __launch_bounds__(256) void init_kernel(
    float* __restrict__ state, float* __restrict__ m_buf,
    const float* __restrict__ b_msg, float* __restrict__ loss_acc,
    float* __restrict__ scal, int* __restrict__ deg)
{
  int stride = gridDim.x * blockDim.x;
  for (int i = blockIdx.x * blockDim.x + threadIdx.x; i < BNH; i += stride) {
    state[i] = 0.f;
    m_buf[i] = b_msg[i & (H - 1)];   // step-0 message = 0 @ W_msg + b_msg
    if (i < N) { loss_acc[i] = 0.f; deg[i] = 0; }
    if (i < 16) scal[i] = 0.f;
  }
}

__global__ __launch_bounds__(256) void hist_kernel(const int* __restrict__ ei, int* __restrict__ deg) {
  int e = blockIdx.x * 256 + threadIdx.x;
  if (e < E) atomicAdd(&deg[ei[E + e]], 1);   // row 1 = dst
}

__global__ __launch_bounds__(1024) void scan_kernel(const int* __restrict__ deg,
    int* __restrict__ row_ptr, int* __restrict__ cursor)
{
  __shared__ int s[N];
  int tid = threadIdx.x;
  s[tid] = deg[tid];
  s[tid + 1024] = deg[tid + 1024];
  __syncthreads();
  for (int off = 1; off < N; off <<= 1) {
    int v0 = (tid >= off) ? s[tid - off] : 0;
    int v1 = s[tid + 1024 - off];           // tid+1024 >= off always (off<=1024)
    __syncthreads();
    s[tid] += v0;
    s[tid + 1024] += v1;
    __syncthreads();
  }
  row_ptr[tid + 1] = s[tid];
  row_ptr[tid + 1025] = s[tid + 1024];
  cursor[tid] = (tid == 0) ? 0 : s[tid - 1];
  cursor[tid + 1024] = s[tid + 1023];
  if (tid == 0) row_ptr[0] = 0;
}

__global__ __launch_bounds__(256) void fill_kernel(const int* __restrict__ ei,
    int* __restrict__ cursor, int* __restrict__ col_src)
{
  int e = blockIdx.x * 256 + threadIdx.x;
  if (e < E) {
    int d = ei[E + e];
    int slot = atomicAdd(&cursor[d], 1);
    col_src[slot] = ei[e];                  // row 0 = src
  }
}

__global__ __launch_bounds__(256) void mask_kernel(const int* __restrict__ mask, float* __restrict__ scal) {
  int stride = gridDim.x * blockDim.x;
  int v = 0;
  for (int i = blockIdx.x * blockDim.x + threadIdx.x; i < B * T * N; i += stride)
    v += (mask[i] != 0);
  for (int o = 1; o < 64; o <<= 1) v += __shfl_xor(v, o, 64);
  if ((threadIdx.x & 63) == 0) atomicAdd(&scal[0], (float)v);
}

// ---------------- per-step kernel 1: aggregate + mix ----------------
// one wave per (b,n): agg[h] = sum_{e: dst==n} m[b,src,h]; m2 = W_mix @ [agg; x_t] + b_mix

__global__ __launch_bounds__(256) void k2_kernel(
    const float* __restrict__ m_buf, const float* __restrict__ x,
    const float* __restrict__ W_mix, const float* __restrict__ b_mix,
    const int* __restrict__ row_ptr, const int* __restrict__ col_src,
    float* __restrict__ m2_buf, int t)
{
  __shared__ float Wr[64 * 130];           // W_mix row-major, stride 130 (even pad)
  for (int i = threadIdx.x; i < 64 * 128; i += 256) {
    int g = i >> 7, f = i & 127;
    Wr[g * 130 + f] = W_mix[i];
  }
  __syncthreads();
  const int lane = threadIdx.x & 63;
  const int waveG = (blockIdx.x * 256 + threadIdx.x) >> 6;   // 0..4095
  const float bm = b_mix[lane];
  const float2* wrow2 = (const float2*)&Wr[lane * 130];
  for (int p = waveG; p < B * N; p += 4096) {
    int b = p >> 11;
    int n = p & (N - 1);
    float aggv = 0.f;
    int e0 = row_ptr[n], e1 = row_ptr[n + 1];
    const float* mb = m_buf + (size_t)b * N * H;
    for (int e = e0; e < e1; ++e)
      aggv += mb[col_src[e] * H + lane];
    float xv = x[(((size_t)b * T + t) * N + n) * F + lane];
    float acc = bm;
#pragma unroll
    for (int j = 0; j < 32; ++j) {
      float2 w = wrow2[j];
      acc += w.x * bcastf(aggv, 2 * j) + w.y * bcastf(aggv, 2 * j + 1);
    }
#pragma unroll
    for (int j = 32; j < 64; ++j) {
      float2 w = wrow2[j];
      acc += w.x * bcastf(xv, 2 * j - 64) + w.y * bcastf(xv, 2 * j - 63);
    }
    m2_buf[(size_t)p * H + lane] = acc;
  }
}

// ---------------- per-step kernel 2: gates + GRU + readout + next message ----------------
// one block (256 thr) per node

__global__ __launch_bounds__(256) void k3_kernel(
    const float* __restrict__ m2_buf, float* __restrict__ state,
    const float* __restrict__ W_ih, const float* __restrict__ W_hh,
    const float* __restrict__ b_ih, const float* __restrict__ b_hh,
    const float* __restrict__ W_msg, const float* __restrict__ b_msg,
    const float* __restrict__ W_read, const float* __restrict__ b_read,
    const float* __restrict__ targets, const int* __restrict__ mask,
    float* __restrict__ m_next, float* __restrict__ loss_acc, int t)
{
  __shared__ float chunk[128 * 66];   // 33.8KB weight stage; reused for W_msg^T in phase D
  __shared__ float m2s[B * H];
  __shared__ float sts[B * H];
  __shared__ float gis[B * G];
  __shared__ float ghs[B * G];
  __shared__ float nss[B * H];

  const int n = blockIdx.x;
  const int tid = threadIdx.x;

  // Phase A: stage m2 and state for this node (all 8 batches)
  for (int i = tid; i < B * H; i += 256) {
    int b = i >> 6, j = i & 63;
    m2s[i] = m2_buf[((size_t)b * N + n) * H + j];
    sts[i] = state[((size_t)b * N + n) * H + j];
  }
  __syncthreads();

  // Phase B: gi/gh. 384 row-units (192 gi rows + 192 gh rows), 3 chunks of 128.
  const int ru = tid & 127;   // row-unit in chunk: 0..63 -> W_ih row, 64..127 -> W_hh row
  const int bh = tid >> 7;    // batch half
#pragma unroll 1
  for (int c = 0; c < 3; ++c) {
    const int g0 = c * 64;
#pragma unroll
    for (int i = 0; i < 8; ++i) {
      int idx4 = tid + 256 * i;             // float4 index, 0..2047
      int mat = idx4 >> 10;
      int row = (idx4 >> 4) & 63;
      int h4 = idx4 & 15;
      const float* srcbase = mat ? W_hh : W_ih;
      const float4 w = *(const float4*)(srcbase + (((size_t)n * G) + g0 + row) * H + h4 * 4);
      float* dp = &chunk[(mat * 64 + row) * 66 + h4 * 4];
      dp[0] = w.x; dp[1] = w.y; dp[2] = w.z; dp[3] = w.w;
    }
    __syncthreads();
    {
      const int mat = ru >> 6;
      const int g = g0 + (ru & 63);
      const float bias = (mat ? b_hh : b_ih)[n * G + g];
      float a0 = bias, a1 = bias, a2 = bias, a3 = bias;
      const float2* wrow = (const float2*)&chunk[ru * 66];          // 8B aligned (66 even)
      const float4* vec = (const float4*)((mat ? sts : m2s) + bh * 4 * H);
#pragma unroll
      for (int h4 = 0; h4 < 16; ++h4) {
        float2 wa = wrow[h4 * 2];
        float2 wb = wrow[h4 * 2 + 1];
        float4 v0 = vec[h4];
        float4 v1 = vec[16 + h4];
        float4 v2 = vec[32 + h4];
        float4 v3 = vec[48 + h4];
        a0 += wa.x * v0.x + wa.y * v0.y + wb.x * v0.z + wb.y * v0.w;
        a1 += wa.x * v1.x + wa.y * v1.y + wb.x * v1.z + wb.y * v1.w;
        a2 += wa.x * v2.x + wa.y * v2.y + wb.x * v2.z + wb.y * v2.w;
        a3 += wa.x * v3.x + wa.y * v3.y + wb.x * v3.z + wb.y * v3.w;
      }
      float* outp = (mat ? ghs : gis) + (bh * 4) * G + g;
      outp[0] = a0; outp[G] = a1; outp[2 * G] = a2; outp[3 * G] = a3;
    }
    __syncthreads();
  }

  // Phase C (wave 0): GRU + readout + loss.  Waves 1-3: stage W_msg^T into chunk.
  if (tid >= 64) {
    for (int i = tid - 64; i < 64 * 64; i += 192) {
      int g = i >> 6, h = i & 63;
      chunk[h * 66 + g] = W_msg[i];          // transposed, stride-66 pad
    }
  } else {
    const int h = tid;
    const float wr = W_read[h];
    const float br = b_read[0];
    float lsum = 0.f;
#pragma unroll
    for (int b = 0; b < B; ++b) {
      float ir = gis[b * G + h],        hr = ghs[b * G + h];
      float iz = gis[b * G + 64 + h],   hz = ghs[b * G + 64 + h];
      float in_ = gis[b * G + 128 + h], hn = ghs[b * G + 128 + h];
      float r = 1.f / (1.f + __expf(-(ir + hr)));
      float z = 1.f / (1.f + __expf(-(iz + hz)));
      float pre = in_ + r * hn;
      float a = __expf(-2.f * fabsf(pre));           // stable tanh
      float nc = copysignf((1.f - a) / (1.f + a), pre);
      float ns = (1.f - z) * nc + z * sts[b * H + h];
      nss[b * H + h] = ns;
      state[((size_t)b * N + n) * H + h] = ns;
      float v = ns * wr;
#pragma unroll
      for (int o = 32; o >= 1; o >>= 1) v += __shfl_xor(v, o, 64);
      if (h == 0) {
        size_t idx = ((size_t)b * T + t) * N + n;
        float d = (v + br) - targets[idx];
        if (mask[idx] != 0) lsum += 0.5f * d * d;
      }
    }
    if (h == 0) loss_acc[n] += lsum;                 // unique block per n; cross-step via launch order
  }
  __syncthreads();

  // Phase D: next message m_next[b,n,:] = W_msg @ new_state + b_msg
  {
    const int g = tid & 63;
    const int bq = tid >> 6;
    const float bm = b_msg[g];
#pragma unroll
    for (int pass = 0; pass < 2; ++pass) {
      const int b = bq + pass * 4;
      float acc = bm;
      const float4* nv = (const float4*)(nss + b * H);
#pragma unroll
      for (int h4 = 0; h4 < 16; ++h4) {
        float4 v = nv[h4];
        acc += v.x * chunk[(h4 * 4 + 0) * 66 + g];
        acc += v.y * chunk[(h4 * 4 + 1) * 66 + g];
        acc += v.z * chunk[(h4 * 4 + 2) * 66 + g];
        acc += v.w * chunk[(h4 * 4 + 3) * 66 + g];
      }
      m_next[((size_t)b * N + n) * H + g] = acc;
    }
  }
}

__global__ __launch_bounds__(256) void final_kernel(const float* __restrict__ loss_acc,
    const float* __restrict__ scal, float* __restrict__ out)
{
  __shared__ float sred[4];
  float v = 0.f;
  for (int i = threadIdx.x; i < N; i += 256) v += loss_acc[i];
  for (int o = 1; o < 64; o <<= 1) v += __shfl_xor(v, o, 64);
  if ((threadIdx.x & 63) == 0) sred[threadIdx.x >> 6] = v;
  __syncthreads();
  if (threadIdx.x == 0) out[0] = (sred[0] + sred[1] + sred[2] + sred[3]) / scal[0];
}

extern "C" void kernel_launch(void* const* d_in, const int* in_sizes, int n_in,
                              void* d_out, int out_size, void* d_ws, size_t ws_size,
                              hipStream_t stream)
{
  const float* x       = (const float*)d_in[0];
  const float* targets = (const float*)d_in[1];
  const int*   mask    = (const int*)d_in[2];
  const int*   ei      = (const int*)d_in[3];
  const float* W_msg   = (const float*)d_in[4];
  const float* b_msg   = (const float*)d_in[5];
  const float* W_mix   = (const float*)d_in[6];
  const float* b_mix   = (const float*)d_in[7];
  const float* W_ih    = (const float*)d_in[8];
  const float* W_hh    = (const float*)d_in[9];
  const float* b_ih    = (const float*)d_in[10];
  const float* b_hh    = (const float*)d_in[11];
  const float* W_read  = (const float*)d_in[12];
  const float* b_read  = (const float*)d_in[13];
  float* out = (float*)d_out;

  float* state    = (float*)d_ws;
  float* m_buf    = state + BNH;
  float* m2_buf   = m_buf + BNH;
  float* loss_acc = m2_buf + BNH;
  float* scal     = loss_acc + N;
  int* deg        = (int*)(scal + 16);
  int* row_ptr    = deg + N;
  int* cursor     = row_ptr + (N + 16);
  int* col_src    = cursor + N;
  // total ws use ~12.8 MB

  init_kernel<<<1024, 256, 0, stream>>>(state, m_buf, b_msg, loss_acc, scal, deg);
  hist_kernel<<<E / 256, 256, 0, stream>>>(ei, deg);
  scan_kernel<<<1, 1024, 0, stream>>>(deg, row_ptr, cursor);
  fill_kernel<<<E / 256, 256, 0, stream>>>(ei, cursor, col_src);
  mask_kernel<<<512, 256, 0, stream>>>(mask, scal);
  for (int t = 0; t < T; ++t) {
    k2_kernel<<<1024, 256, 0, stream>>>(m_buf, x, W_mix, b_mix, row_ptr, col_src, m2_buf, t);
    k3_kernel<<<N, 256, 0, stream>>>(m2_buf, state, W_ih, W_hh, b_ih, b_hh,
                                     W_msg, b_msg, W_read, b_read,
                                     targets, mask, m_buf, loss_acc, t);
  }
  final_kernel<<<1, 256, 0, stream>>>(loss_acc, scal, out);
}

// Round 2
// 2553.572 us; speedup vs baseline: 3.7238x; 3.7238x over previous
//
#include <hip/hip_runtime.h>
#include <math.h>

namespace {
constexpr int B = 8, T = 64, N = 2048, H = 64, F = 64, E = 32768, G = 192;
constexpr int BNH = B * N * H;   // 1048576
constexpr int NWELEM = N * G * H;  // 25165824 per weight tensor
}

typedef __attribute__((ext_vector_type(8))) short bfrag;   // 8 bf16 = 4 VGPRs
typedef __attribute__((ext_vector_type(4))) float ffrag;   // 4 fp32 acc

#define MFMA(a, b, c) __builtin_amdgcn_mfma_f32_16x16x32_bf16(a, b, c, 0, 0, 0)

__device__ __forceinline__ unsigned short f2bf(float f) {
  unsigned u = __float_as_uint(f);
  u += 0x7fffu + ((u >> 16) & 1u);   // RNE
  return (unsigned short)(u >> 16);
}

// ---------------- setup kernels ----------------

__global__ __launch_bounds__(256) void init_kernel(
    float* __restrict__ state, float* __restrict__ mA,
    const float* __restrict__ b_msg, float* __restrict__ loss_acc,
    float* __restrict__ scal, int* __restrict__ deg)
{
  int stride = gridDim.x * blockDim.x;
  for (int i = blockIdx.x * blockDim.x + threadIdx.x; i < BNH; i += stride) {
    state[i] = 0.f;
    mA[i] = b_msg[i & (H - 1)];       // step-0 message = 0 @ W_msg + b_msg
    if (i < N) { loss_acc[i] = 0.f; deg[i] = 0; }
    if (i < 16) scal[i] = 0.f;
  }
}

__global__ __launch_bounds__(256) void conv_kernel(
    const float* __restrict__ Wi, const float* __restrict__ Wh,
    const float* __restrict__ Wm, const float* __restrict__ Wg,
    unsigned short* __restrict__ Wib, unsigned short* __restrict__ Whb,
    unsigned short* __restrict__ Wmb, unsigned short* __restrict__ Wgb)
{
  int stride = gridDim.x * blockDim.x;
  for (int i = blockIdx.x * blockDim.x + threadIdx.x; i < NWELEM; i += stride) {
    Wib[i] = f2bf(Wi[i]);
    Whb[i] = f2bf(Wh[i]);
    if (i < 64 * 128) Wmb[i] = f2bf(Wm[i]);
    if (i < 64 * 64) Wgb[i] = f2bf(Wg[i]);
  }
}

__global__ __launch_bounds__(256) void hist_kernel(const int* __restrict__ ei, int* __restrict__ deg) {
  int e = blockIdx.x * 256 + threadIdx.x;
  if (e < E) atomicAdd(&deg[ei[E + e]], 1);   // row 1 = dst
}

__global__ __launch_bounds__(1024) void scan_kernel(const int* __restrict__ deg,
    int* __restrict__ row_ptr, int* __restrict__ cursor)
{
  __shared__ int s[N];
  int tid = threadIdx.x;
  s[tid] = deg[tid];
  s[tid + 1024] = deg[tid + 1024];
  __syncthreads();
  for (int off = 1; off < N; off <<= 1) {
    int v0 = (tid >= off) ? s[tid - off] : 0;
    int v1 = s[tid + 1024 - off];
    __syncthreads();
    s[tid] += v0;
    s[tid + 1024] += v1;
    __syncthreads();
  }
  row_ptr[tid + 1] = s[tid];
  row_ptr[tid + 1025] = s[tid + 1024];
  cursor[tid] = (tid == 0) ? 0 : s[tid - 1];
  cursor[tid + 1024] = s[tid + 1023];
  if (tid == 0) row_ptr[0] = 0;
}

__global__ __launch_bounds__(256) void fill_kernel(const int* __restrict__ ei,
    int* __restrict__ cursor, int* __restrict__ col_src)
{
  int e = blockIdx.x * 256 + threadIdx.x;
  if (e < E) {
    int d = ei[E + e];
    int slot = atomicAdd(&cursor[d], 1);
    col_src[slot] = ei[e];                  // row 0 = src
  }
}

__global__ __launch_bounds__(256) void mask_kernel(const int* __restrict__ mask, float* __restrict__ scal) {
  int stride = gridDim.x * blockDim.x;
  int v = 0;
  for (int i = blockIdx.x * blockDim.x + threadIdx.x; i < B * T * N; i += stride)
    v += (mask[i] != 0);
  for (int o = 1; o < 64; o <<= 1) v += __shfl_xor(v, o, 64);
  if ((threadIdx.x & 63) == 0) atomicAdd(&scal[0], (float)v);
}

// ---------------- per-step fused kernel ----------------
// one block (256 thr, 4 waves) per node. All matvecs via bf16 MFMA 16x16x32,
// M=batch(8 of 16 rows used), weights' B-fragments loaded straight from global.

__global__ __launch_bounds__(256) void step_kernel(
    const float* __restrict__ x, const float* __restrict__ targets,
    const int* __restrict__ mask, float* __restrict__ state,
    const unsigned short* __restrict__ W_ihb, const unsigned short* __restrict__ W_hhb,
    const unsigned short* __restrict__ W_mixb, const unsigned short* __restrict__ W_msgb,
    const float* __restrict__ b_ih, const float* __restrict__ b_hh,
    const float* __restrict__ b_mix, const float* __restrict__ b_msg,
    const float* __restrict__ W_read, const float* __restrict__ b_read,
    const int* __restrict__ row_ptr, const int* __restrict__ col_src,
    const float* __restrict__ m_cur, float* __restrict__ m_nxt,
    float* __restrict__ loss_acc, int t)
{
  __shared__ float sts[B * H];            // state, fp32, for pointwise
  __shared__ unsigned short aggA[B * 72]; // A-frag layouts, bf16, pad 72 (rows 16B-aligned)
  __shared__ unsigned short stsA[B * 72];
  __shared__ unsigned short m2A[B * 72];
  __shared__ unsigned short nsA[B * 72];
  __shared__ float gis[B * G];
  __shared__ float ghs[B * G];
  __shared__ float red[B];

  const int n = blockIdx.x;
  const int tid = threadIdx.x;
  const int w = tid >> 6, lane = tid & 63;
  const int mrow = lane & 15, quad = lane >> 4;

  // ---- Phase A: state load + edge gather (wave w handles batches 2w, 2w+1)
  {
    const int h = lane;
    const int b0 = 2 * w, b1 = 2 * w + 1;
    float s0 = state[((size_t)b0 * N + n) * H + h];
    float s1 = state[((size_t)b1 * N + n) * H + h];
    sts[b0 * H + h] = s0; sts[b1 * H + h] = s1;
    stsA[b0 * 72 + h] = f2bf(s0); stsA[b1 * 72 + h] = f2bf(s1);
    float a0 = 0.f, a1 = 0.f;
    const int e0 = row_ptr[n], e1 = row_ptr[n + 1];
    const float* mb0 = m_cur + (size_t)b0 * N * H;
    const float* mb1 = m_cur + (size_t)b1 * N * H;
    for (int e = e0; e < e1; ++e) {
      int src = col_src[e] * H;
      a0 += mb0[src + h];
      a1 += mb1[src + h];
    }
    aggA[b0 * 72 + h] = f2bf(a0); aggA[b1 * 72 + h] = f2bf(a1);
  }
  __syncthreads();

  // ---- Phase B1: m2 = W_mix @ [agg; x] (+b_mix). Wave w -> m2 cols [16w,16w+16)
  {
    const int g0 = w * 16;
    bfrag za = (bfrag)0;
    bfrag a0 = (mrow < 8) ? *(const bfrag*)&aggA[mrow * 72 + quad * 8] : za;
    bfrag a1 = (mrow < 8) ? *(const bfrag*)&aggA[mrow * 72 + 32 + quad * 8] : za;
    bfrag a2 = za, a3 = za;
    if (mrow < 8) {
      const float* xp = x + (((size_t)mrow * T + t) * N + n) * F;
      float xv[8];
      *(float4*)&xv[0] = *(const float4*)(xp + quad * 8);
      *(float4*)&xv[4] = *(const float4*)(xp + quad * 8 + 4);
#pragma unroll
      for (int j = 0; j < 8; ++j) a2[j] = (short)f2bf(xv[j]);
      *(float4*)&xv[0] = *(const float4*)(xp + 32 + quad * 8);
      *(float4*)&xv[4] = *(const float4*)(xp + 32 + quad * 8 + 4);
#pragma unroll
      for (int j = 0; j < 8; ++j) a3[j] = (short)f2bf(xv[j]);
    }
    const unsigned short* wm = W_mixb + (g0 + mrow) * 128 + quad * 8;
    ffrag acc = {0.f, 0.f, 0.f, 0.f};
    acc = MFMA(a0, *(const bfrag*)(wm), acc);
    acc = MFMA(a1, *(const bfrag*)(wm + 32), acc);
    acc = MFMA(a2, *(const bfrag*)(wm + 64), acc);
    acc = MFMA(a3, *(const bfrag*)(wm + 96), acc);
    if (quad < 2) {
      float bm = b_mix[g0 + mrow];
#pragma unroll
      for (int r = 0; r < 4; ++r)
        m2A[(quad * 4 + r) * 72 + g0 + mrow] = f2bf(acc[r] + bm);
    }
  }
  __syncthreads();

  // ---- Phase B2: gi = m2 @ W_ih^T, gh = state @ W_hh^T. 12+12 tiles over 4 waves.
  {
    bfrag za = (bfrag)0;
    bfrag am0 = (mrow < 8) ? *(const bfrag*)&m2A[mrow * 72 + quad * 8] : za;
    bfrag am1 = (mrow < 8) ? *(const bfrag*)&m2A[mrow * 72 + 32 + quad * 8] : za;
    bfrag as0 = (mrow < 8) ? *(const bfrag*)&stsA[mrow * 72 + quad * 8] : za;
    bfrag as1 = (mrow < 8) ? *(const bfrag*)&stsA[mrow * 72 + 32 + quad * 8] : za;
    const unsigned short* Wi = W_ihb + (size_t)n * G * H;
    const unsigned short* Wh = W_hhb + (size_t)n * G * H;
#pragma unroll
    for (int tt = 0; tt < 3; ++tt) {
      const int g0 = (w + tt * 4) * 16;
      const unsigned short* wri = Wi + (g0 + mrow) * H + quad * 8;
      const unsigned short* wrh = Wh + (g0 + mrow) * H + quad * 8;
      ffrag ai = {0.f, 0.f, 0.f, 0.f};
      ffrag ah = {0.f, 0.f, 0.f, 0.f};
      ai = MFMA(am0, *(const bfrag*)(wri), ai);
      ai = MFMA(am1, *(const bfrag*)(wri + 32), ai);
      ah = MFMA(as0, *(const bfrag*)(wrh), ah);
      ah = MFMA(as1, *(const bfrag*)(wrh + 32), ah);
      if (quad < 2) {
#pragma unroll
        for (int r = 0; r < 4; ++r) {
          gis[(quad * 4 + r) * G + g0 + mrow] = ai[r];
          ghs[(quad * 4 + r) * G + g0 + mrow] = ah[r];
        }
      }
    }
  }
  __syncthreads();

  // ---- Phase C: GRU pointwise + readout + loss. Wave w -> batches 2w, 2w+1.
  {
    const int h = lane;
    const float bir = b_ih[n * G + h], biz = b_ih[n * G + 64 + h], bin_ = b_ih[n * G + 128 + h];
    const float bhr = b_hh[n * G + h], bhz = b_hh[n * G + 64 + h], bhn = b_hh[n * G + 128 + h];
    const float wrd = W_read[h];
    const float br = b_read[0];
#pragma unroll
    for (int bb = 0; bb < 2; ++bb) {
      const int b = 2 * w + bb;
      float ir = gis[b * G + h] + bir;
      float iz = gis[b * G + 64 + h] + biz;
      float in_ = gis[b * G + 128 + h] + bin_;
      float hr = ghs[b * G + h] + bhr;
      float hz = ghs[b * G + 64 + h] + bhz;
      float hn = ghs[b * G + 128 + h] + bhn;
      float r = 1.f / (1.f + __expf(-(ir + hr)));
      float z = 1.f / (1.f + __expf(-(iz + hz)));
      float pre = in_ + r * hn;
      float a = __expf(-2.f * fabsf(pre));
      float nc = copysignf((1.f - a) / (1.f + a), pre);   // stable tanh
      float ns = (1.f - z) * nc + z * sts[b * H + h];
      state[((size_t)b * N + n) * H + h] = ns;
      nsA[b * 72 + h] = f2bf(ns);
      float v = ns * wrd;
#pragma unroll
      for (int o = 32; o >= 1; o >>= 1) v += __shfl_xor(v, o, 64);
      if (h == 0) {
        size_t idx = ((size_t)b * T + t) * N + n;
        float d = (v + br) - targets[idx];
        red[b] = (mask[idx] != 0) ? 0.5f * d * d : 0.f;
      }
    }
  }
  __syncthreads();

  // ---- Phase D: m_next = W_msg @ ns + b_msg. Wave w -> cols [16w,16w+16)
  {
    const int g0 = w * 16;
    bfrag za = (bfrag)0;
    bfrag an0 = (mrow < 8) ? *(const bfrag*)&nsA[mrow * 72 + quad * 8] : za;
    bfrag an1 = (mrow < 8) ? *(const bfrag*)&nsA[mrow * 72 + 32 + quad * 8] : za;
    const unsigned short* wg = W_msgb + (g0 + mrow) * H + quad * 8;
    ffrag acc = {0.f, 0.f, 0.f, 0.f};
    acc = MFMA(an0, *(const bfrag*)(wg), acc);
    acc = MFMA(an1, *(const bfrag*)(wg + 32), acc);
    if (quad < 2) {
      float bm = b_msg[g0 + mrow];
#pragma unroll
      for (int r = 0; r < 4; ++r)
        m_nxt[((size_t)(quad * 4 + r) * N + n) * H + g0 + mrow] = acc[r] + bm;
    }
  }
  if (tid == 0) {
    float s = red[0] + red[1] + red[2] + red[3] + red[4] + red[5] + red[6] + red[7];
    loss_acc[n] += s;
  }
}

__global__ __launch_bounds__(256) void final_kernel(const float* __restrict__ loss_acc,
    const float* __restrict__ scal, float* __restrict__ out)
{
  __shared__ float sred[4];
  float v = 0.f;
  for (int i = threadIdx.x; i < N; i += 256) v += loss_acc[i];
  for (int o = 1; o < 64; o <<= 1) v += __shfl_xor(v, o, 64);
  if ((threadIdx.x & 63) == 0) sred[threadIdx.x >> 6] = v;
  __syncthreads();
  if (threadIdx.x == 0) out[0] = (sred[0] + sred[1] + sred[2] + sred[3]) / scal[0];
}

extern "C" void kernel_launch(void* const* d_in, const int* in_sizes, int n_in,
                              void* d_out, int out_size, void* d_ws, size_t ws_size,
                              hipStream_t stream)
{
  const float* x       = (const float*)d_in[0];
  const float* targets = (const float*)d_in[1];
  const int*   mask    = (const int*)d_in[2];
  const int*   ei      = (const int*)d_in[3];
  const float* W_msg   = (const float*)d_in[4];
  const float* b_msg   = (const float*)d_in[5];
  const float* W_mix   = (const float*)d_in[6];
  const float* b_mix   = (const float*)d_in[7];
  const float* W_ih    = (const float*)d_in[8];
  const float* W_hh    = (const float*)d_in[9];
  const float* b_ih    = (const float*)d_in[10];
  const float* b_hh    = (const float*)d_in[11];
  const float* W_read  = (const float*)d_in[12];
  const float* b_read  = (const float*)d_in[13];
  float* out = (float*)d_out;

  float* state    = (float*)d_ws;
  float* mA       = state + BNH;
  float* mB       = mA + BNH;
  float* loss_acc = mB + BNH;
  float* scal     = loss_acc + N;
  int* deg        = (int*)(scal + 16);
  int* row_ptr    = deg + N;
  int* cursor     = row_ptr + (N + 16);
  int* col_src    = cursor + N;
  unsigned short* W_ihb  = (unsigned short*)(col_src + E);   // 16B aligned (checked)
  unsigned short* W_hhb  = W_ihb + NWELEM;
  unsigned short* W_mixb = W_hhb + NWELEM;
  unsigned short* W_msgb = W_mixb + 64 * 128;
  // total ws use ~113 MB

  init_kernel<<<1024, 256, 0, stream>>>(state, mA, b_msg, loss_acc, scal, deg);
  conv_kernel<<<8192, 256, 0, stream>>>(W_ih, W_hh, W_mix, W_msg, W_ihb, W_hhb, W_mixb, W_msgb);
  hist_kernel<<<E / 256, 256, 0, stream>>>(ei, deg);
  scan_kernel<<<1, 1024, 0, stream>>>(deg, row_ptr, cursor);
  fill_kernel<<<E / 256, 256, 0, stream>>>(ei, cursor, col_src);
  mask_kernel<<<512, 256, 0, stream>>>(mask, scal);

  float* mcur = mA;
  float* mnxt = mB;
  for (int t = 0; t < T; ++t) {
    step_kernel<<<N, 256, 0, stream>>>(x, targets, mask, state,
                                       W_ihb, W_hhb, W_mixb, W_msgb,
                                       b_ih, b_hh, b_mix, b_msg, W_read, b_read,
                                       row_ptr, col_src, mcur, mnxt, loss_acc, t);
    float* tmp = mcur; mcur = mnxt; mnxt = tmp;
  }
  final_kernel<<<1, 256, 0, stream>>>(loss_acc, scal, out);
}